// Round 1
// baseline (984.918 us; speedup 1.0000x reference)
//
#include <hip/hip_runtime.h>

#define NODES  50000
#define EDGES  800000
#define GRAPHS 1024
#define P      200      // uniform row pitch (floats) for all node-feature buffers

// ---------------------------------------------------------------------------
// CSR build (per launch; deterministic work, atomic order only affects fp sum
// order which is threshold-tolerated)
// ---------------------------------------------------------------------------
__global__ void hist_kernel(const int* __restrict__ dst, int* __restrict__ deg) {
    int e = blockIdx.x * blockDim.x + threadIdx.x;
    if (e < EDGES) atomicAdd(&deg[dst[e]], 1);
}

__global__ void scan_kernel(const int* __restrict__ deg,
                            int* __restrict__ rowstart, int* __restrict__ cursor) {
    __shared__ int part[1024];
    int t = threadIdx.x;
    const int CH = (NODES + 1023) / 1024;   // 49
    int base = t * CH;
    int s = 0;
    for (int i = 0; i < CH; i++) {
        int n = base + i;
        if (n < NODES) s += deg[n];
    }
    part[t] = s;
    __syncthreads();
    for (int off = 1; off < 1024; off <<= 1) {
        int v = 0;
        if (t >= off) v = part[t - off];
        __syncthreads();
        if (t >= off) part[t] += v;
        __syncthreads();
    }
    int run = (t == 0) ? 0 : part[t - 1];   // exclusive prefix of this chunk
    for (int i = 0; i < CH; i++) {
        int n = base + i;
        if (n < NODES) {
            rowstart[n] = run;
            cursor[n]   = run;
            run += deg[n];
        }
    }
    if (t == 0) rowstart[NODES] = EDGES;
}

__global__ void scatter_kernel(const int* __restrict__ src, const int* __restrict__ dst,
                               int* __restrict__ cursor, int* __restrict__ csrc) {
    int e = blockIdx.x * blockDim.x + threadIdx.x;
    if (e < EDGES) {
        int p = atomicAdd(&cursor[dst[e]], 1);
        csrc[p] = src[e];
    }
}

// ---------------------------------------------------------------------------
// Aggregation: one wave per destination node, register accumulation, no atomics
// ---------------------------------------------------------------------------
template<int D>
__global__ void csr_agg(const float* __restrict__ feat, int fpitch,
                        const int* __restrict__ rowstart, const int* __restrict__ csrc,
                        float* __restrict__ agg) {
    int wid  = (blockIdx.x * blockDim.x + threadIdx.x) >> 6;
    int lane = threadIdx.x & 63;
    if (wid >= NODES) return;
    constexpr int NI = (D + 63) / 64;
    float s[NI];
#pragma unroll
    for (int i = 0; i < NI; i++) s[i] = 0.0f;
    int r0 = rowstart[wid], r1 = rowstart[wid + 1];
    for (int r = r0; r < r1; r++) {
        int sn = csrc[r];
        const float* fp = feat + (size_t)sn * fpitch;
#pragma unroll
        for (int i = 0; i < NI; i++) {
            int c = lane + 64 * i;
            if (c < D) s[i] += fp[c];
        }
    }
    float* ap = agg + (size_t)wid * P;
#pragma unroll
    for (int i = 0; i < NI; i++) {
        int c = lane + 64 * i;
        if (c < D) ap[c] = s[i];
    }
}

// ---------------------------------------------------------------------------
// GEMM: OUT[m][n] = relu( (X[m]+A2[m]) @ W + B ), optional BN-stat epilogue.
// 64-node tile in LDS, 16x16 threads, 4 rows x TN cols per thread.
// In-place OUT==A2 is safe: each block reads only its own 64 rows (staged
// fully before any write) and writes only its own rows.
// ---------------------------------------------------------------------------
template<int K, int N, bool ADD2, bool STATS>
__launch_bounds__(256)
__global__ void gemm_kernel(const float* __restrict__ X, int xpitch,
                            const float* __restrict__ A2,
                            const float* __restrict__ W, const float* __restrict__ B,
                            float* __restrict__ OUT,
                            float* __restrict__ gsum, float* __restrict__ gsq) {
    constexpr int LP = K + ((K % 32 == 0) ? 1 : 0);   // pad only when stride hits 1 bank
    constexpr int TN = (N + 15) / 16;
    __shared__ float As[64 * LP];
    __shared__ float shSum[STATS ? N : 1];
    __shared__ float shSq[STATS ? N : 1];

    int tid   = threadIdx.x;
    int node0 = blockIdx.x * 64;

    if (STATS && tid < N) { shSum[tid] = 0.0f; shSq[tid] = 0.0f; }

    // stage A tile (X + optional A2) into LDS
    for (int idx = tid; idx < 64 * K; idx += 256) {
        int r = idx / K;
        int c = idx - r * K;
        int gn = node0 + r;
        float v = 0.0f;
        if (gn < NODES) {
            v = X[(size_t)gn * xpitch + c];
            if (ADD2) v += A2[(size_t)gn * P + c];
        }
        As[r * LP + c] = v;
    }
    __syncthreads();

    int ty = tid >> 4, tx = tid & 15;
    float acc[4][TN];
#pragma unroll
    for (int j = 0; j < TN; j++) {
        int n = tx + 16 * j;
        float bv = (n < N) ? B[n] : 0.0f;
#pragma unroll
        for (int i = 0; i < 4; i++) acc[i][j] = bv;
    }

    for (int k = 0; k < K; k++) {
        float av[4];
#pragma unroll
        for (int i = 0; i < 4; i++) av[i] = As[(ty * 4 + i) * LP + k];
#pragma unroll
        for (int j = 0; j < TN; j++) {
            int n = tx + 16 * j;
            float wv = (n < N) ? W[k * N + n] : 0.0f;
#pragma unroll
            for (int i = 0; i < 4; i++) acc[i][j] = fmaf(av[i], wv, acc[i][j]);
        }
    }

    // relu + store + (optional) per-feature stats
#pragma unroll
    for (int j = 0; j < TN; j++) {
        int n = tx + 16 * j;
        if (n < N) {
            float s = 0.0f, q = 0.0f;
#pragma unroll
            for (int i = 0; i < 4; i++) {
                int gn = node0 + ty * 4 + i;
                float v = acc[i][j];
                v = v > 0.0f ? v : 0.0f;
                if (gn < NODES) {
                    OUT[(size_t)gn * P + n] = v;
                    if (STATS) { s += v; q += v * v; }
                }
            }
            if (STATS) { atomicAdd(&shSum[n], s); atomicAdd(&shSq[n], q); }
        }
    }
    if (STATS) {
        __syncthreads();
        if (tid < N) {
            atomicAdd(&gsum[tid], shSum[tid]);
            atomicAdd(&gsq[tid], shSq[tid]);
        }
    }
}

// ---------------------------------------------------------------------------
// BN finalize + apply
// ---------------------------------------------------------------------------
template<int N>
__global__ void bn_finalize(const float* __restrict__ sum, const float* __restrict__ sq,
                            const float* __restrict__ gamma, const float* __restrict__ beta,
                            float* __restrict__ scale, float* __restrict__ shift) {
    int n = threadIdx.x;
    if (n < N) {
        float mean = sum[n] * (1.0f / NODES);
        float var  = sq[n] * (1.0f / NODES) - mean * mean;
        var = var < 0.0f ? 0.0f : var;
        float sc = gamma[n] * rsqrtf(var + 1e-5f);
        scale[n] = sc;
        shift[n] = beta[n] - mean * sc;
    }
}

template<int N>
__global__ void bn_apply(float* __restrict__ h, const float* __restrict__ scale,
                         const float* __restrict__ shift) {
    long idx = (long)blockIdx.x * blockDim.x + threadIdx.x;
    if (idx >= (long)NODES * P) return;
    int c = (int)(idx % P);
    if (c < N) h[idx] = fmaf(h[idx], scale[c], shift[c]);
}

// ---------------------------------------------------------------------------
// Pool + head MLP
// ---------------------------------------------------------------------------
__global__ void pool_kernel(const float* __restrict__ h, const int* __restrict__ batch,
                            float* __restrict__ g) {
    int idx = blockIdx.x * blockDim.x + threadIdx.x;
    if (idx >= NODES * 32) return;
    int n = idx >> 5, f = idx & 31;
    atomicAdd(&g[batch[n] * 32 + f], h[(size_t)n * P + f]);
}

__global__ void head_kernel(const float* __restrict__ g,
                            const float* __restrict__ fw1, const float* __restrict__ fb1,
                            const float* __restrict__ fw2, const float* __restrict__ fb2,
                            const float* __restrict__ ow, const float* __restrict__ ob,
                            float* __restrict__ out) {
    int gi = blockIdx.x * blockDim.x + threadIdx.x;
    if (gi >= GRAPHS) return;
    float v[32];
#pragma unroll
    for (int k = 0; k < 32; k++) v[k] = g[gi * 32 + k];
    float a1[16];
#pragma unroll
    for (int o = 0; o < 16; o++) {
        float s = fb1[o];
#pragma unroll
        for (int k = 0; k < 32; k++) s = fmaf(v[k], fw1[k * 16 + o], s);
        a1[o] = s > 0.0f ? s : 0.0f;
    }
    float a2[8];
#pragma unroll
    for (int o = 0; o < 8; o++) {
        float s = fb2[o];
#pragma unroll
        for (int k = 0; k < 16; k++) s = fmaf(a1[k], fw2[k * 8 + o], s);
        a2[o] = s > 0.0f ? s : 0.0f;
    }
#pragma unroll
    for (int o = 0; o < 2; o++) {
        float s = ob[o];
#pragma unroll
        for (int k = 0; k < 8; k++) s = fmaf(a2[k], ow[k * 2 + o], s);
        out[gi * 2 + o] = s;
    }
}

// ---------------------------------------------------------------------------
extern "C" void kernel_launch(void* const* d_in, const int* in_sizes, int n_in,
                              void* d_out, int out_size, void* d_ws, size_t ws_size,
                              hipStream_t stream) {
    const float* x     = (const float*)d_in[0];
    const int*   ei    = (const int*)d_in[1];
    const int*   batch = (const int*)d_in[2];
    const float *w1a = (const float*)d_in[3],  *b1a = (const float*)d_in[4];
    const float *w1b = (const float*)d_in[5],  *b1b = (const float*)d_in[6];
    const float *g1  = (const float*)d_in[7],  *be1 = (const float*)d_in[8];
    const float *w2a = (const float*)d_in[9],  *b2a = (const float*)d_in[10];
    const float *w2b = (const float*)d_in[11], *b2b = (const float*)d_in[12];
    const float *g2  = (const float*)d_in[13], *be2 = (const float*)d_in[14];
    const float *w3a = (const float*)d_in[15], *b3a = (const float*)d_in[16];
    const float *w3b = (const float*)d_in[17], *b3b = (const float*)d_in[18];
    const float *g3  = (const float*)d_in[19], *be3 = (const float*)d_in[20];
    const float *fw1 = (const float*)d_in[21], *fb1 = (const float*)d_in[22];
    const float *fw2 = (const float*)d_in[23], *fb2 = (const float*)d_in[24];
    const float *ow  = (const float*)d_in[25], *ob  = (const float*)d_in[26];
    const int* src = ei;
    const int* dst = ei + EDGES;

    float* ws    = (float*)d_ws;
    float* AGG   = ws;                                  // 50000 x 200
    float* H     = ws + (size_t)NODES * P;              // 50000 x 200
    float* SUM   = ws + (size_t)2 * NODES * P;          // 256
    float* SQ    = SUM + 256;
    float* SCALE = SUM + 512;
    float* SHIFT = SUM + 768;
    float* G     = SUM + 1024;                          // 1024 x 32
    int*   deg      = (int*)(G + GRAPHS * 32);          // 50000
    int*   rowstart = deg + NODES;                      // 50001
    int*   cursor   = rowstart + NODES + 1;             // 50000
    int*   csrc     = cursor + NODES;                   // 800000
    float* out = (float*)d_out;

    const int GB = (NODES + 63) / 64;       // gemm blocks
    const int AB = (NODES * 64 + 255) / 256; // agg blocks (wave per node)
    const int EB = (EDGES + 255) / 256;

    // ---- CSR build (shared by all 3 layers) ----
    hipMemsetAsync(deg, 0, NODES * sizeof(int), stream);
    hist_kernel<<<EB, 256, 0, stream>>>(dst, deg);
    scan_kernel<<<1, 1024, 0, stream>>>(deg, rowstart, cursor);
    scatter_kernel<<<EB, 256, 0, stream>>>(src, dst, cursor, csrc);

    // ---- layer 1 (114 -> 198 -> 198) ----
    csr_agg<114><<<AB, 256, 0, stream>>>(x, 114, rowstart, csrc, AGG);
    gemm_kernel<114, 198, true, false><<<GB, 256, 0, stream>>>(x, 114, AGG, w1a, b1a, AGG, nullptr, nullptr);
    hipMemsetAsync(SUM, 0, 512 * sizeof(float), stream);
    gemm_kernel<198, 198, false, true><<<GB, 256, 0, stream>>>(AGG, P, nullptr, w1b, b1b, H, SUM, SQ);
    bn_finalize<198><<<1, 256, 0, stream>>>(SUM, SQ, g1, be1, SCALE, SHIFT);
    bn_apply<198><<<(NODES * P + 255) / 256, 256, 0, stream>>>(H, SCALE, SHIFT);

    // ---- layer 2 (198 -> 64 -> 64) ----
    csr_agg<198><<<AB, 256, 0, stream>>>(H, P, rowstart, csrc, AGG);
    gemm_kernel<198, 64, true, false><<<GB, 256, 0, stream>>>(H, P, AGG, w2a, b2a, AGG, nullptr, nullptr);
    hipMemsetAsync(SUM, 0, 512 * sizeof(float), stream);
    gemm_kernel<64, 64, false, true><<<GB, 256, 0, stream>>>(AGG, P, nullptr, w2b, b2b, H, SUM, SQ);
    bn_finalize<64><<<1, 256, 0, stream>>>(SUM, SQ, g2, be2, SCALE, SHIFT);
    bn_apply<64><<<(NODES * P + 255) / 256, 256, 0, stream>>>(H, SCALE, SHIFT);

    // ---- layer 3 (64 -> 32 -> 32) ----
    csr_agg<64><<<AB, 256, 0, stream>>>(H, P, rowstart, csrc, AGG);
    gemm_kernel<64, 32, true, false><<<GB, 256, 0, stream>>>(H, P, AGG, w3a, b3a, AGG, nullptr, nullptr);
    hipMemsetAsync(SUM, 0, 512 * sizeof(float), stream);
    gemm_kernel<32, 32, false, true><<<GB, 256, 0, stream>>>(AGG, P, nullptr, w3b, b3b, H, SUM, SQ);
    bn_finalize<32><<<1, 256, 0, stream>>>(SUM, SQ, g3, be3, SCALE, SHIFT);
    bn_apply<32><<<(NODES * P + 255) / 256, 256, 0, stream>>>(H, SCALE, SHIFT);

    // ---- pool + head ----
    hipMemsetAsync(G, 0, GRAPHS * 32 * sizeof(float), stream);
    pool_kernel<<<(NODES * 32 + 255) / 256, 256, 0, stream>>>(H, batch, G);
    head_kernel<<<(GRAPHS + 255) / 256, 256, 0, stream>>>(G, fw1, fb1, fw2, fb2, ow, ob, out);
}